// Round 1
// baseline (136.273 us; speedup 1.0000x reference)
//
#include <hip/hip_runtime.h>
#include <math.h>

#define EPS 1e-8

// Cyclic Jacobi eigensolver for symmetric 3x3 (double precision).
// On exit: A is diagonalized in-place (w = diag), Q columns are eigenvectors,
// i.e. original A = Q diag(w) Q^T.
__device__ __forceinline__ void eigh3(double A[3][3], double Q[3][3], double w[3]) {
    Q[0][0] = 1.0; Q[0][1] = 0.0; Q[0][2] = 0.0;
    Q[1][0] = 0.0; Q[1][1] = 1.0; Q[1][2] = 0.0;
    Q[2][0] = 0.0; Q[2][1] = 0.0; Q[2][2] = 1.0;
    for (int sweep = 0; sweep < 10; ++sweep) {
        double off = A[0][1]*A[0][1] + A[0][2]*A[0][2] + A[1][2]*A[1][2];
        if (off < 1e-26) break;
        #pragma unroll
        for (int p = 0; p < 2; ++p) {
            #pragma unroll
            for (int q0 = 0; q0 < 2; ++q0) {
                int q = p + 1 + q0;
                if (q > 2) continue;
                double apq = A[p][q];
                if (apq == 0.0) continue;
                double theta = (A[q][q] - A[p][p]) / (2.0 * apq);
                double t = copysign(1.0, theta) / (fabs(theta) + sqrt(theta*theta + 1.0));
                double c = 1.0 / sqrt(t*t + 1.0);
                double s = t * c;
                int r = 3 - p - q;  // the remaining index
                double app = A[p][p], aqq = A[q][q];
                A[p][p] = app - t * apq;
                A[q][q] = aqq + t * apq;
                A[p][q] = 0.0; A[q][p] = 0.0;
                double arp = A[r][p], arq = A[r][q];
                A[r][p] = c*arp - s*arq; A[p][r] = A[r][p];
                A[r][q] = c*arq + s*arp; A[q][r] = A[r][q];
                #pragma unroll
                for (int i = 0; i < 3; ++i) {
                    double qip = Q[i][p], qiq = Q[i][q];
                    Q[i][p] = c*qip - s*qiq;
                    Q[i][q] = s*qip + c*qiq;
                }
            }
        }
    }
    w[0] = A[0][0]; w[1] = A[1][1]; w[2] = A[2][2];
}

__global__ __launch_bounds__(256) void wasserstein_log_kernel(
    const float* __restrict__ miu1, const float* __restrict__ miu2,
    const float* __restrict__ cov1, const float* __restrict__ cov2,
    float* __restrict__ out, int B)
{
    int b = blockIdx.x * blockDim.x + threadIdx.x;
    if (b >= B) return;

    // ---- output 0: miu_2 - miu_1 ----
    out[3*b + 0] = miu2[3*b + 0] - miu1[3*b + 0];
    out[3*b + 1] = miu2[3*b + 1] - miu1[3*b + 1];
    out[3*b + 2] = miu2[3*b + 2] - miu1[3*b + 2];

    // ---- load covariances (promote to double) ----
    double c1[3][3], c2m[3][3];
    #pragma unroll
    for (int i = 0; i < 3; ++i)
        #pragma unroll
        for (int j = 0; j < 3; ++j) {
            c1[i][j]  = (double)cov1[9*b + 3*i + j];
            c2m[i][j] = (double)cov2[9*b + 3*i + j];
        }

    // ---- A_sqrt = sqrtm(cov1 + EPS*I) via eigh ----
    double A[3][3];
    #pragma unroll
    for (int i = 0; i < 3; ++i)
        #pragma unroll
        for (int j = 0; j < 3; ++j)
            A[i][j] = c1[i][j] + (i == j ? EPS : 0.0);

    double Q[3][3], w[3];
    eigh3(A, Q, w);
    double s0 = sqrt(fabs(w[0])), s1 = sqrt(fabs(w[1])), s2 = sqrt(fabs(w[2]));

    double S[3][3];
    #pragma unroll
    for (int i = 0; i < 3; ++i)
        #pragma unroll
        for (int j = 0; j < 3; ++j)
            S[i][j] = Q[i][0]*s0*Q[j][0] + Q[i][1]*s1*Q[j][1] + Q[i][2]*s2*Q[j][2];

    // ---- Sinv = inv(S + EPS*I) (general 3x3 adjugate) ----
    double a00 = S[0][0] + EPS, a01 = S[0][1],       a02 = S[0][2];
    double a10 = S[1][0],       a11 = S[1][1] + EPS, a12 = S[1][2];
    double a20 = S[2][0],       a21 = S[2][1],       a22 = S[2][2] + EPS;
    double det = a00*(a11*a22 - a12*a21) - a01*(a10*a22 - a12*a20) + a02*(a10*a21 - a11*a20);
    double idet = 1.0 / det;
    double Sinv[3][3];
    Sinv[0][0] = (a11*a22 - a12*a21) * idet;
    Sinv[0][1] = (a02*a21 - a01*a22) * idet;
    Sinv[0][2] = (a01*a12 - a02*a11) * idet;
    Sinv[1][0] = (a12*a20 - a10*a22) * idet;
    Sinv[1][1] = (a00*a22 - a02*a20) * idet;
    Sinv[1][2] = (a02*a10 - a00*a12) * idet;
    Sinv[2][0] = (a10*a21 - a11*a20) * idet;
    Sinv[2][1] = (a01*a20 - a00*a21) * idet;
    Sinv[2][2] = (a00*a11 - a01*a10) * idet;

    // ---- C = S * cov2 * S^T + EPS*I ----
    double T[3][3];
    #pragma unroll
    for (int i = 0; i < 3; ++i)
        #pragma unroll
        for (int k = 0; k < 3; ++k)
            T[i][k] = S[i][0]*c2m[0][k] + S[i][1]*c2m[1][k] + S[i][2]*c2m[2][k];
    double C[3][3];
    #pragma unroll
    for (int i = 0; i < 3; ++i)
        #pragma unroll
        for (int l = 0; l < 3; ++l)
            C[i][l] = T[i][0]*S[l][0] + T[i][1]*S[l][1] + T[i][2]*S[l][2]
                      + (i == l ? EPS : 0.0);

    // ---- C_sqrt via second eigh ----
    double Qc[3][3], wc[3];
    eigh3(C, Qc, wc);
    double t0 = sqrt(fabs(wc[0])), t1 = sqrt(fabs(wc[1])), t2 = sqrt(fabs(wc[2]));
    double Csq[3][3];
    #pragma unroll
    for (int i = 0; i < 3; ++i)
        #pragma unroll
        for (int j = 0; j < 3; ++j)
            Csq[i][j] = Qc[i][0]*t0*Qc[j][0] + Qc[i][1]*t1*Qc[j][1] + Qc[i][2]*t2*Qc[j][2];

    // ---- V = S * Csq * Sinv^T ----
    double T2[3][3];
    #pragma unroll
    for (int i = 0; i < 3; ++i)
        #pragma unroll
        for (int k = 0; k < 3; ++k)
            T2[i][k] = S[i][0]*Csq[0][k] + S[i][1]*Csq[1][k] + S[i][2]*Csq[2][k];
    double V[3][3];
    #pragma unroll
    for (int i = 0; i < 3; ++i)
        #pragma unroll
        for (int l = 0; l < 3; ++l)
            V[i][l] = T2[i][0]*Sinv[l][0] + T2[i][1]*Sinv[l][1] + T2[i][2]*Sinv[l][2];

    // ---- cov_velocity = V + V^T - 2*cov1 ----
    float* out_cov = out + (size_t)3 * B;
    #pragma unroll
    for (int i = 0; i < 3; ++i)
        #pragma unroll
        for (int j = 0; j < 3; ++j)
            out_cov[9*b + 3*i + j] = (float)(V[i][j] + V[j][i] - 2.0*c1[i][j]);
}

extern "C" void kernel_launch(void* const* d_in, const int* in_sizes, int n_in,
                              void* d_out, int out_size, void* d_ws, size_t ws_size,
                              hipStream_t stream) {
    const float* miu1 = (const float*)d_in[0];
    const float* miu2 = (const float*)d_in[1];
    const float* cov1 = (const float*)d_in[2];
    const float* cov2 = (const float*)d_in[3];
    float* out = (float*)d_out;
    int B = in_sizes[0] / 3;  // miu_1 is (B,3)
    int threads = 256;
    int blocks = (B + threads - 1) / threads;
    hipLaunchKernelGGL(wasserstein_log_kernel, dim3(blocks), dim3(threads), 0, stream,
                       miu1, miu2, cov1, cov2, out, B);
}

// Round 2
// 108.450 us; speedup vs baseline: 1.2566x; 1.2566x over previous
//
#include <hip/hip_runtime.h>
#include <math.h>

#define EPS 1e-8f

// One branchless Jacobi rotation on pair (p,q), bystander r.
// Uses native v_rcp_f32 / v_rsq_f32 (~1-2 ulp) — accuracy is ample for the
// 0.14 absmax threshold (fp32 jax reference has the same error structure).
__device__ __forceinline__ void jrot(float A[3][3], float Q[3][3], int p, int q, int r) {
    float apq  = A[p][q];
    float diff = A[q][q] - A[p][p];
    float theta = diff * __builtin_amdgcn_rcpf(2.0f * apq);     // may be +-inf/NaN
    float t = __builtin_amdgcn_rcpf(fabsf(theta) + sqrtf(fmaf(theta, theta, 1.0f)));
    t = copysignf(t, theta);
    t = (fabsf(apq) < 1e-30f) ? 0.0f : t;                       // kill inf/NaN path
    float c = __builtin_amdgcn_rsqf(fmaf(t, t, 1.0f));
    float s = t * c;
    float tapq = t * apq;
    A[p][p] -= tapq;
    A[q][q] += tapq;
    A[p][q] = 0.0f; A[q][p] = 0.0f;
    float arp = A[r][p], arq = A[r][q];
    A[r][p] = fmaf(c, arp, -s * arq); A[p][r] = A[r][p];
    A[r][q] = fmaf(c, arq,  s * arp); A[q][r] = A[r][q];
    #pragma unroll
    for (int i = 0; i < 3; ++i) {
        float qip = Q[i][p], qiq = Q[i][q];
        Q[i][p] = fmaf(c, qip, -s * qiq);
        Q[i][q] = fmaf(s, qip,  c * qiq);
    }
}

// Cyclic Jacobi, fixed 5 sweeps (branchless, wave-uniform). A -> diag(w), Q eigvecs.
__device__ __forceinline__ void eigh3f(float A[3][3], float Q[3][3]) {
    Q[0][0] = 1.0f; Q[0][1] = 0.0f; Q[0][2] = 0.0f;
    Q[1][0] = 0.0f; Q[1][1] = 1.0f; Q[1][2] = 0.0f;
    Q[2][0] = 0.0f; Q[2][1] = 0.0f; Q[2][2] = 1.0f;
    #pragma unroll
    for (int sweep = 0; sweep < 5; ++sweep) {
        jrot(A, Q, 0, 1, 2);
        jrot(A, Q, 0, 2, 1);
        jrot(A, Q, 1, 2, 0);
    }
}

__global__ __launch_bounds__(256) void wasserstein_log_kernel(
    const float* __restrict__ miu1, const float* __restrict__ miu2,
    const float* __restrict__ cov1, const float* __restrict__ cov2,
    float* __restrict__ out, int B)
{
    int b = blockIdx.x * blockDim.x + threadIdx.x;
    if (b >= B) return;

    // ---- output 0: miu_2 - miu_1 ----
    out[3*b + 0] = miu2[3*b + 0] - miu1[3*b + 0];
    out[3*b + 1] = miu2[3*b + 1] - miu1[3*b + 1];
    out[3*b + 2] = miu2[3*b + 2] - miu1[3*b + 2];

    // ---- load covariances ----
    float c1[3][3], c2m[3][3];
    #pragma unroll
    for (int i = 0; i < 3; ++i)
        #pragma unroll
        for (int j = 0; j < 3; ++j) {
            c1[i][j]  = cov1[9*b + 3*i + j];
            c2m[i][j] = cov2[9*b + 3*i + j];
        }

    // ---- eigh(cov1 + EPS*I) ----
    float A[3][3];
    #pragma unroll
    for (int i = 0; i < 3; ++i)
        #pragma unroll
        for (int j = 0; j < 3; ++j)
            A[i][j] = c1[i][j] + (i == j ? EPS : 0.0f);
    float Q[3][3];
    eigh3f(A, Q);

    // s_k = |w_k|^(1/2);  sinv_k = 1/(s_k + EPS)   (== inv(A_sqrt + EPS*I) in eigenbasis)
    float s[3], si[3];
    #pragma unroll
    for (int k = 0; k < 3; ++k) {
        s[k]  = sqrtf(fabsf(A[k][k]));
        si[k] = __builtin_amdgcn_rcpf(s[k] + EPS);
    }

    // S = Q diag(s) Q^T ;  Sinv = Q diag(si) Q^T   (both exactly symmetric)
    float S[3][3], Sinv[3][3];
    #pragma unroll
    for (int i = 0; i < 3; ++i)
        #pragma unroll
        for (int j = 0; j < 3; ++j) {
            S[i][j]    = fmaf(Q[i][0]*s[0],  Q[j][0], fmaf(Q[i][1]*s[1],  Q[j][1], Q[i][2]*s[2]  * Q[j][2]));
            Sinv[i][j] = fmaf(Q[i][0]*si[0], Q[j][0], fmaf(Q[i][1]*si[1], Q[j][1], Q[i][2]*si[2] * Q[j][2]));
        }

    // ---- C = S * cov2 * S^T + EPS*I ----
    float T[3][3];
    #pragma unroll
    for (int i = 0; i < 3; ++i)
        #pragma unroll
        for (int k = 0; k < 3; ++k)
            T[i][k] = fmaf(S[i][0], c2m[0][k], fmaf(S[i][1], c2m[1][k], S[i][2]*c2m[2][k]));
    float C[3][3];
    #pragma unroll
    for (int i = 0; i < 3; ++i)
        #pragma unroll
        for (int l = 0; l < 3; ++l)
            C[i][l] = fmaf(T[i][0], S[l][0], fmaf(T[i][1], S[l][1], T[i][2]*S[l][2]))
                      + (i == l ? EPS : 0.0f);

    // ---- C_sqrt via second eigh ----
    float Qc[3][3];
    eigh3f(C, Qc);
    float t0 = sqrtf(fabsf(C[0][0])), t1 = sqrtf(fabsf(C[1][1])), t2 = sqrtf(fabsf(C[2][2]));
    float Csq[3][3];
    #pragma unroll
    for (int i = 0; i < 3; ++i)
        #pragma unroll
        for (int j = 0; j < 3; ++j)
            Csq[i][j] = fmaf(Qc[i][0]*t0, Qc[j][0], fmaf(Qc[i][1]*t1, Qc[j][1], Qc[i][2]*t2 * Qc[j][2]));

    // ---- V = S * Csq * Sinv (Sinv symmetric) ----
    float T2[3][3];
    #pragma unroll
    for (int i = 0; i < 3; ++i)
        #pragma unroll
        for (int k = 0; k < 3; ++k)
            T2[i][k] = fmaf(S[i][0], Csq[0][k], fmaf(S[i][1], Csq[1][k], S[i][2]*Csq[2][k]));
    float V[3][3];
    #pragma unroll
    for (int i = 0; i < 3; ++i)
        #pragma unroll
        for (int l = 0; l < 3; ++l)
            V[i][l] = fmaf(T2[i][0], Sinv[l][0], fmaf(T2[i][1], Sinv[l][1], T2[i][2]*Sinv[l][2]));

    // ---- cov_velocity = V + V^T - 2*cov1 ----
    float* out_cov = out + (size_t)3 * B;
    #pragma unroll
    for (int i = 0; i < 3; ++i)
        #pragma unroll
        for (int j = 0; j < 3; ++j)
            out_cov[9*b + 3*i + j] = V[i][j] + V[j][i] - 2.0f*c1[i][j];
}

extern "C" void kernel_launch(void* const* d_in, const int* in_sizes, int n_in,
                              void* d_out, int out_size, void* d_ws, size_t ws_size,
                              hipStream_t stream) {
    const float* miu1 = (const float*)d_in[0];
    const float* miu2 = (const float*)d_in[1];
    const float* cov1 = (const float*)d_in[2];
    const float* cov2 = (const float*)d_in[3];
    float* out = (float*)d_out;
    int B = in_sizes[0] / 3;
    int threads = 256;
    int blocks = (B + threads - 1) / threads;
    hipLaunchKernelGGL(wasserstein_log_kernel, dim3(blocks), dim3(threads), 0, stream,
                       miu1, miu2, cov1, cov2, out, B);
}

// Round 3
// 105.238 us; speedup vs baseline: 1.2949x; 1.0305x over previous
//
#include <hip/hip_runtime.h>
#include <math.h>

#define EPS 1e-8f

// Jacobi rotation on (p,q), bystander r. 3 transcendentals (rsq,sqrt,rcp).
// cos2t = |h| * rsqrt(h^2 + 4 apq^2), h = aqq - app; sign(h) folded into s.
// |h|+1e-18 bias: keeps radicand >= 1e-36 (normal), so h=apq=0 gives the
// identity rotation (c=1,s=0) instead of inf/NaN.
__device__ __forceinline__ void jrot(float A[3][3], float Q[3][3], int p, int q, int r) {
    float apq  = A[p][q];
    float h    = A[q][q] - A[p][p];
    float ah   = fabsf(h) + 1e-18f;
    float v    = apq + apq;
    float rad  = fmaf(ah, ah, v * v);
    float rr   = __builtin_amdgcn_rsqf(rad);
    float c2   = ah * rr;                       // cos 2theta in [0,1]
    float s2h  = apq * rr;                      // sin2theta/2 (sign of apq)
    s2h = (h < 0.0f) ? -s2h : s2h;              // apply sign(h)
    float c    = sqrtf(fmaf(0.5f, c2, 0.5f));   // c >= sqrt(1/2)
    float rc   = __builtin_amdgcn_rcpf(c);
    float s    = s2h * rc;                      // sin theta
    float t    = s * rc;                        // tan theta
    float tapq = t * apq;
    A[p][p] -= tapq;
    A[q][q] += tapq;
    A[p][q] = 0.0f; A[q][p] = 0.0f;
    float arp = A[r][p], arq = A[r][q];
    A[r][p] = fmaf(c, arp, -s * arq); A[p][r] = A[r][p];
    A[r][q] = fmaf(c, arq,  s * arp); A[q][r] = A[r][q];
    #pragma unroll
    for (int i = 0; i < 3; ++i) {
        float qip = Q[i][p], qiq = Q[i][q];
        Q[i][p] = fmaf(c, qip, -s * qiq);
        Q[i][q] = fmaf(s, qip,  c * qiq);
    }
}

// Cyclic Jacobi, fixed 4 sweeps (branchless). A -> diag(w) in place, Q eigvecs.
__device__ __forceinline__ void eigh3f(float A[3][3], float Q[3][3]) {
    Q[0][0] = 1.0f; Q[0][1] = 0.0f; Q[0][2] = 0.0f;
    Q[1][0] = 0.0f; Q[1][1] = 1.0f; Q[1][2] = 0.0f;
    Q[2][0] = 0.0f; Q[2][1] = 0.0f; Q[2][2] = 1.0f;
    #pragma unroll
    for (int sweep = 0; sweep < 4; ++sweep) {
        jrot(A, Q, 0, 1, 2);
        jrot(A, Q, 0, 2, 1);
        jrot(A, Q, 1, 2, 0);
    }
}

__global__ __launch_bounds__(256) void wasserstein_log_kernel(
    const float* __restrict__ miu1, const float* __restrict__ miu2,
    const float* __restrict__ cov1, const float* __restrict__ cov2,
    float* __restrict__ out, int B, int B2)
{
    int b0 = blockIdx.x * blockDim.x + threadIdx.x;
    if (b0 >= B2) return;
    float* out_cov = out + (size_t)3 * B;

    // Two independent elements per thread: b0 and b0 + B2 (independent
    // dependency chains -> hides rsq/sqrt/rcp latency).
    #pragma unroll
    for (int e = 0; e < 2; ++e) {
        int b = b0 + e * B2;
        if (b >= B) continue;

        // ---- output 0: miu_2 - miu_1 ----
        out[3*b + 0] = miu2[3*b + 0] - miu1[3*b + 0];
        out[3*b + 1] = miu2[3*b + 1] - miu1[3*b + 1];
        out[3*b + 2] = miu2[3*b + 2] - miu1[3*b + 2];

        // ---- load cov1 (keep 6 unique entries for the epilogue), cov2 ----
        float A[3][3], M[3][3];
        #pragma unroll
        for (int i = 0; i < 3; ++i)
            #pragma unroll
            for (int j = 0; j < 3; ++j) {
                A[i][j] = cov1[9*b + 3*i + j];
                M[i][j] = cov2[9*b + 3*i + j];
            }
        float k00 = A[0][0], k01 = A[0][1], k02 = A[0][2];
        float k11 = A[1][1], k12 = A[1][2], k22 = A[2][2];
        A[0][0] += EPS; A[1][1] += EPS; A[2][2] += EPS;

        // ---- eigh(cov1 + eps I) = Q diag(w) Q^T ----
        float Q[3][3];
        eigh3f(A, Q);

        // d = sqrt(w), di = 1/sqrt(w)  (one rsq + one mul per eigenvalue;
        // the reference's +eps on A_sqrt before inv is 3e-7 relative - negligible)
        float d[3], di[3];
        #pragma unroll
        for (int k = 0; k < 3; ++k) {
            float w = fmaxf(fabsf(A[k][k]), 1e-12f);
            di[k] = __builtin_amdgcn_rsqf(w);
            d[k]  = w * di[k];
        }

        // ---- G = Q^T M Q (rotate cov2 into cov1's eigenbasis) ----
        float T[3][3];
        #pragma unroll
        for (int i = 0; i < 3; ++i)
            #pragma unroll
            for (int j = 0; j < 3; ++j)
                T[i][j] = fmaf(Q[0][i], M[0][j], fmaf(Q[1][i], M[1][j], Q[2][i]*M[2][j]));
        float Cp[3][3];
        #pragma unroll
        for (int i = 0; i < 3; ++i)
            #pragma unroll
            for (int j = 0; j < 3; ++j) {
                float g = fmaf(T[i][0], Q[0][j], fmaf(T[i][1], Q[1][j], T[i][2]*Q[2][j]));
                Cp[i][j] = d[i] * d[j] * g + (i == j ? EPS : 0.0f);  // C' = D G D + eps I
            }

        // ---- eigh(C') -> Qc, wc ;  tsq = sqrt(|wc|) ----
        float Qc[3][3];
        eigh3f(Cp, Qc);
        float tsq[3];
        #pragma unroll
        for (int k = 0; k < 3; ++k) {
            float wc = fmaxf(fabsf(Cp[k][k]), 1e-12f);
            tsq[k] = wc * __builtin_amdgcn_rsqf(wc);
        }

        // ---- V = (Q D Qc) diag(tsq) (Q D^-1 Qc)^T ----
        float U[3][3], P[3][3];
        #pragma unroll
        for (int i = 0; i < 3; ++i)
            #pragma unroll
            for (int j = 0; j < 3; ++j) {
                float q0 = Q[i][0], q1 = Q[i][1], q2 = Q[i][2];
                U[i][j] = fmaf(q0*d[0],  Qc[0][j], fmaf(q1*d[1],  Qc[1][j], q2*d[2]  * Qc[2][j]));
                P[i][j] = fmaf(q0*di[0], Qc[0][j], fmaf(q1*di[1], Qc[1][j], q2*di[2] * Qc[2][j]));
            }
        float V[3][3];
        #pragma unroll
        for (int i = 0; i < 3; ++i)
            #pragma unroll
            for (int j = 0; j < 3; ++j)
                V[i][j] = fmaf(U[i][0]*tsq[0], P[j][0],
                          fmaf(U[i][1]*tsq[1], P[j][1], U[i][2]*tsq[2] * P[j][2]));

        // ---- cov_velocity = V + V^T - 2 cov1 ----
        out_cov[9*b + 0] = V[0][0] + V[0][0] - 2.0f*k00;
        out_cov[9*b + 1] = V[0][1] + V[1][0] - 2.0f*k01;
        out_cov[9*b + 2] = V[0][2] + V[2][0] - 2.0f*k02;
        out_cov[9*b + 3] = V[1][0] + V[0][1] - 2.0f*k01;
        out_cov[9*b + 4] = V[1][1] + V[1][1] - 2.0f*k11;
        out_cov[9*b + 5] = V[1][2] + V[2][1] - 2.0f*k12;
        out_cov[9*b + 6] = V[2][0] + V[0][2] - 2.0f*k02;
        out_cov[9*b + 7] = V[2][1] + V[1][2] - 2.0f*k12;
        out_cov[9*b + 8] = V[2][2] + V[2][2] - 2.0f*k22;
    }
}

extern "C" void kernel_launch(void* const* d_in, const int* in_sizes, int n_in,
                              void* d_out, int out_size, void* d_ws, size_t ws_size,
                              hipStream_t stream) {
    const float* miu1 = (const float*)d_in[0];
    const float* miu2 = (const float*)d_in[1];
    const float* cov1 = (const float*)d_in[2];
    const float* cov2 = (const float*)d_in[3];
    float* out = (float*)d_out;
    int B  = in_sizes[0] / 3;
    int B2 = (B + 1) / 2;
    int threads = 256;
    int blocks = (B2 + threads - 1) / threads;
    hipLaunchKernelGGL(wasserstein_log_kernel, dim3(blocks), dim3(threads), 0, stream,
                       miu1, miu2, cov1, cov2, out, B, B2);
}

// Round 4
// 97.606 us; speedup vs baseline: 1.3962x; 1.0782x over previous
//
#include <hip/hip_runtime.h>
#include <math.h>

#define EPS 1e-8f

// Jacobi angle for 2x2 block [[app,apq],[apq,aqq]]: returns c,s and the two
// rotated diagonal values. Only 2 transcendentals (both v_rsq_f32).
//   r = sqrt(h^2 + 4 apq^2), cos2t = |h|/r, c = sqrt((1+cos2t)/2),
//   s = sign(h)*apq/(r*c),   |t*apq| = (r-|h|)/2  (exact identity).
// |h|+1e-18 bias => rad>=1e-36 (normal); h=apq=0 yields identity rotation.
__device__ __forceinline__ void jangle(float app, float aqq, float apq,
                                       float &c, float &s, float &app2, float &aqq2) {
    float h     = aqq - app;
    float ah    = fabsf(h) + 1e-18f;
    float v     = apq + apq;
    float rad   = fmaf(ah, ah, v * v);
    float rr    = __builtin_amdgcn_rsqf(rad);
    float c2h   = fmaf(0.5f * ah, rr, 0.5f);      // cos^2(theta) in (0.5, 1]
    float rc2   = __builtin_amdgcn_rsqf(c2h);
    c = c2h * rc2;
    float apq_s = (h < 0.0f) ? -apq : apq;
    s = apq_s * (rr * rc2);
    float dl    = copysignf(0.5f * (rad * rr - ah), h);   // t*apq, signed
    app2 = app - dl;
    aqq2 = aqq + dl;
}

// 3-sweep cyclic Jacobi on symmetric (a00..a22); Q (q00..q22) = eigenvectors,
// diagonal -> eigenvalues. Sweep 1 specialized for Q == identity.
__device__ __forceinline__ void eigh3(
    float &a00, float &a01, float &a02, float &a11, float &a12, float &a22,
    float &q00, float &q01, float &q02,
    float &q10, float &q11, float &q12,
    float &q20, float &q21, float &q22)
{
    float c, s, x, y, t0, t1;
    // ---- sweep 1 (Q specialized) ----
    jangle(a00, a11, a01, c, s, x, y); a00 = x; a11 = y; a01 = 0.0f;
    t0 = a02; t1 = a12; a02 = fmaf(c, t0, -s * t1); a12 = fmaf(c, t1, s * t0);
    q00 = c; q01 = s; q10 = -s; q11 = c;          // col2 == e3 still

    jangle(a00, a22, a02, c, s, x, y); a00 = x; a22 = y; a02 = 0.0f;
    t0 = a01; t1 = a12; a01 = fmaf(c, t0, -s * t1); a12 = fmaf(c, t1, s * t0);
    q02 = s * q00; q12 = s * q10; q20 = -s; q22 = c;
    q00 = c * q00; q10 = c * q10;                  // q21 == 0 still

    jangle(a11, a22, a12, c, s, x, y); a11 = x; a22 = y; a12 = 0.0f;
    t0 = a01; t1 = a02; a01 = fmaf(c, t0, -s * t1); a02 = fmaf(c, t1, s * t0);
    t0 = q01; t1 = q02; q01 = fmaf(c, t0, -s * t1); q02 = fmaf(s, t0, c * t1);
    t0 = q11; t1 = q12; q11 = fmaf(c, t0, -s * t1); q12 = fmaf(s, t0, c * t1);
    q21 = -s * q22; q22 = c * q22;

    // ---- sweeps 2..3 (generic) ----
    #pragma unroll
    for (int sw = 0; sw < 2; ++sw) {
        jangle(a00, a11, a01, c, s, x, y); a00 = x; a11 = y; a01 = 0.0f;
        t0 = a02; t1 = a12; a02 = fmaf(c, t0, -s * t1); a12 = fmaf(c, t1, s * t0);
        t0 = q00; t1 = q01; q00 = fmaf(c, t0, -s * t1); q01 = fmaf(s, t0, c * t1);
        t0 = q10; t1 = q11; q10 = fmaf(c, t0, -s * t1); q11 = fmaf(s, t0, c * t1);
        t0 = q20; t1 = q21; q20 = fmaf(c, t0, -s * t1); q21 = fmaf(s, t0, c * t1);

        jangle(a00, a22, a02, c, s, x, y); a00 = x; a22 = y; a02 = 0.0f;
        t0 = a01; t1 = a12; a01 = fmaf(c, t0, -s * t1); a12 = fmaf(c, t1, s * t0);
        t0 = q00; t1 = q02; q00 = fmaf(c, t0, -s * t1); q02 = fmaf(s, t0, c * t1);
        t0 = q10; t1 = q12; q10 = fmaf(c, t0, -s * t1); q12 = fmaf(s, t0, c * t1);
        t0 = q20; t1 = q22; q20 = fmaf(c, t0, -s * t1); q22 = fmaf(s, t0, c * t1);

        jangle(a11, a22, a12, c, s, x, y); a11 = x; a22 = y; a12 = 0.0f;
        t0 = a01; t1 = a02; a01 = fmaf(c, t0, -s * t1); a02 = fmaf(c, t1, s * t0);
        t0 = q01; t1 = q02; q01 = fmaf(c, t0, -s * t1); q02 = fmaf(s, t0, c * t1);
        t0 = q11; t1 = q12; q11 = fmaf(c, t0, -s * t1); q12 = fmaf(s, t0, c * t1);
        t0 = q21; t1 = q22; q21 = fmaf(c, t0, -s * t1); q22 = fmaf(s, t0, c * t1);
    }
}

__global__ __launch_bounds__(256, 7) void wasserstein_log_kernel(
    const float* __restrict__ miu1, const float* __restrict__ miu2,
    const float* __restrict__ cov1, const float* __restrict__ cov2,
    float* __restrict__ out, int B)
{
    int b = blockIdx.x * blockDim.x + threadIdx.x;
    if (b >= B) return;

    // ---- output 0: miu_2 - miu_1 ----
    out[3*b + 0] = miu2[3*b + 0] - miu1[3*b + 0];
    out[3*b + 1] = miu2[3*b + 1] - miu1[3*b + 1];
    out[3*b + 2] = miu2[3*b + 2] - miu1[3*b + 2];

    // ---- load symmetric inputs (inputs are bitwise-symmetric by construction) ----
    const float* c1p = cov1 + 9*(size_t)b;
    const float* c2p = cov2 + 9*(size_t)b;
    float k00 = c1p[0], k01 = c1p[1], k02 = c1p[2],
          k11 = c1p[4], k12 = c1p[5], k22 = c1p[8];
    float m00 = c2p[0], m01 = c2p[1], m02 = c2p[2],
          m11 = c2p[4], m12 = c2p[5], m22 = c2p[8];

    // ---- eigh(cov1 + eps I) ----
    float a00 = k00 + EPS, a01 = k01, a02 = k02,
          a11 = k11 + EPS, a12 = k12, a22 = k22 + EPS;
    float q00, q01, q02, q10, q11, q12, q20, q21, q22;
    eigh3(a00, a01, a02, a11, a12, a22,
          q00, q01, q02, q10, q11, q12, q20, q21, q22);

    float w0 = fmaxf(fabsf(a00), 1e-12f);
    float w1 = fmaxf(fabsf(a11), 1e-12f);
    float w2 = fmaxf(fabsf(a22), 1e-12f);
    float di0 = __builtin_amdgcn_rsqf(w0), di1 = __builtin_amdgcn_rsqf(w1),
          di2 = __builtin_amdgcn_rsqf(w2);
    float d0 = w0 * di0, d1 = w1 * di1, d2 = w2 * di2;   // sqrt(w)

    // ---- T = M Q ; G = Q^T T (symmetric, 6 entries) ----
    float T00 = fmaf(m00, q00, fmaf(m01, q10, m02 * q20));
    float T01 = fmaf(m00, q01, fmaf(m01, q11, m02 * q21));
    float T02 = fmaf(m00, q02, fmaf(m01, q12, m02 * q22));
    float T10 = fmaf(m01, q00, fmaf(m11, q10, m12 * q20));
    float T11 = fmaf(m01, q01, fmaf(m11, q11, m12 * q21));
    float T12 = fmaf(m01, q02, fmaf(m11, q12, m12 * q22));
    float T20 = fmaf(m02, q00, fmaf(m12, q10, m22 * q20));
    float T21 = fmaf(m02, q01, fmaf(m12, q11, m22 * q21));
    float T22 = fmaf(m02, q02, fmaf(m12, q12, m22 * q22));

    float g00 = fmaf(q00, T00, fmaf(q10, T10, q20 * T20));
    float g01 = fmaf(q00, T01, fmaf(q10, T11, q20 * T21));
    float g02 = fmaf(q00, T02, fmaf(q10, T12, q20 * T22));
    float g11 = fmaf(q01, T01, fmaf(q11, T11, q21 * T21));
    float g12 = fmaf(q01, T02, fmaf(q11, T12, q21 * T22));
    float g22 = fmaf(q02, T02, fmaf(q12, T12, q22 * T22));

    // ---- C' = D G D + eps I  (d_i*d_i == w_i) ----
    float cp00 = fmaf(w0, g00, EPS);
    float cp11 = fmaf(w1, g11, EPS);
    float cp22 = fmaf(w2, g22, EPS);
    float cp01 = d0 * d1 * g01;
    float cp02 = d0 * d2 * g02;
    float cp12 = d1 * d2 * g12;

    // ---- eigh(C') ----
    float e00, e01, e02, e10, e11, e12, e20, e21, e22;
    eigh3(cp00, cp01, cp02, cp11, cp12, cp22,
          e00, e01, e02, e10, e11, e12, e20, e21, e22);
    float u0 = fmaxf(fabsf(cp00), 1e-12f);
    float u1 = fmaxf(fabsf(cp11), 1e-12f);
    float u2 = fmaxf(fabsf(cp22), 1e-12f);
    float ts0 = u0 * __builtin_amdgcn_rsqf(u0);   // sqrt eigenvalues of C'
    float ts1 = u1 * __builtin_amdgcn_rsqf(u1);
    float ts2 = u2 * __builtin_amdgcn_rsqf(u2);

    // ---- U = Q D Qc, P = Q D^-1 Qc ----
    float Ed00 = d0*e00, Ed01 = d0*e01, Ed02 = d0*e02;
    float Ed10 = d1*e10, Ed11 = d1*e11, Ed12 = d1*e12;
    float Ed20 = d2*e20, Ed21 = d2*e21, Ed22 = d2*e22;
    float Ei00 = di0*e00, Ei01 = di0*e01, Ei02 = di0*e02;
    float Ei10 = di1*e10, Ei11 = di1*e11, Ei12 = di1*e12;
    float Ei20 = di2*e20, Ei21 = di2*e21, Ei22 = di2*e22;

    float U00 = fmaf(q00, Ed00, fmaf(q01, Ed10, q02 * Ed20));
    float U01 = fmaf(q00, Ed01, fmaf(q01, Ed11, q02 * Ed21));
    float U02 = fmaf(q00, Ed02, fmaf(q01, Ed12, q02 * Ed22));
    float U10 = fmaf(q10, Ed00, fmaf(q11, Ed10, q12 * Ed20));
    float U11 = fmaf(q10, Ed01, fmaf(q11, Ed11, q12 * Ed21));
    float U12 = fmaf(q10, Ed02, fmaf(q11, Ed12, q12 * Ed22));
    float U20 = fmaf(q20, Ed00, fmaf(q21, Ed10, q22 * Ed20));
    float U21 = fmaf(q20, Ed01, fmaf(q21, Ed11, q22 * Ed21));
    float U22 = fmaf(q20, Ed02, fmaf(q21, Ed12, q22 * Ed22));

    float P00 = fmaf(q00, Ei00, fmaf(q01, Ei10, q02 * Ei20));
    float P01 = fmaf(q00, Ei01, fmaf(q01, Ei11, q02 * Ei21));
    float P02 = fmaf(q00, Ei02, fmaf(q01, Ei12, q02 * Ei22));
    float P10 = fmaf(q10, Ei00, fmaf(q11, Ei10, q12 * Ei20));
    float P11 = fmaf(q10, Ei01, fmaf(q11, Ei11, q12 * Ei21));
    float P12 = fmaf(q10, Ei02, fmaf(q11, Ei12, q12 * Ei22));
    float P20 = fmaf(q20, Ei00, fmaf(q21, Ei10, q22 * Ei20));
    float P21 = fmaf(q20, Ei01, fmaf(q21, Ei11, q22 * Ei21));
    float P22 = fmaf(q20, Ei02, fmaf(q21, Ei12, q22 * Ei22));

    // ---- W = V + V^T = U diag(ts) P^T + P diag(ts) U^T (symmetric) ----
    float A0 = ts0 * U00, A1 = ts1 * U01, A2 = ts2 * U02;
    float B0 = ts0 * U10, B1 = ts1 * U11, B2 = ts2 * U12;
    float C0 = ts0 * U20, C1 = ts1 * U21, C2 = ts2 * U22;

    float W00 = 2.0f * fmaf(A0, P00, fmaf(A1, P01, A2 * P02));
    float W11 = 2.0f * fmaf(B0, P10, fmaf(B1, P11, B2 * P12));
    float W22 = 2.0f * fmaf(C0, P20, fmaf(C1, P21, C2 * P22));
    float W01 = fmaf(A0, P10, fmaf(A1, P11, fmaf(A2, P12,
                fmaf(B0, P00, fmaf(B1, P01, B2 * P02)))));
    float W02 = fmaf(A0, P20, fmaf(A1, P21, fmaf(A2, P22,
                fmaf(C0, P00, fmaf(C1, P01, C2 * P02)))));
    float W12 = fmaf(B0, P20, fmaf(B1, P21, fmaf(B2, P22,
                fmaf(C0, P10, fmaf(C1, P11, C2 * P12)))));

    // ---- cov_velocity = W - 2 cov1 ----
    float o00 = fmaf(-2.0f, k00, W00);
    float o01 = fmaf(-2.0f, k01, W01);
    float o02 = fmaf(-2.0f, k02, W02);
    float o11 = fmaf(-2.0f, k11, W11);
    float o12 = fmaf(-2.0f, k12, W12);
    float o22 = fmaf(-2.0f, k22, W22);

    float* oc = out + (size_t)3 * B + 9*(size_t)b;
    oc[0] = o00; oc[1] = o01; oc[2] = o02;
    oc[3] = o01; oc[4] = o11; oc[5] = o12;
    oc[6] = o02; oc[7] = o12; oc[8] = o22;
}

extern "C" void kernel_launch(void* const* d_in, const int* in_sizes, int n_in,
                              void* d_out, int out_size, void* d_ws, size_t ws_size,
                              hipStream_t stream) {
    const float* miu1 = (const float*)d_in[0];
    const float* miu2 = (const float*)d_in[1];
    const float* cov1 = (const float*)d_in[2];
    const float* cov2 = (const float*)d_in[3];
    float* out = (float*)d_out;
    int B = in_sizes[0] / 3;
    int threads = 256;
    int blocks = (B + threads - 1) / threads;
    hipLaunchKernelGGL(wasserstein_log_kernel, dim3(blocks), dim3(threads), 0, stream,
                       miu1, miu2, cov1, cov2, out, B);
}